// Round 1
// baseline (50.084 us; speedup 1.0000x reference)
//
#include <hip/hip_runtime.h>
#include <math.h>

#define SEQ_LEN 4096
#define KSZ 128
#define OUT_LEN 3969
#define BATCH 8192
#define NB_MAX 1024

// Main pass: one grid-stride loop over batch rows.
// Per row: streaming sum (float4), stash first/last 127 elems to LDS,
// block-reduce (total, edge-corr), sigmoid -> dconv, accumulate
// G[j] += dconv*x[j] (j<127), H[m] += dconv*x[3969+m], C0 += dconv*total,
// db += dconv.  Per-block partials (256 floats) go to workspace.
__global__ __launch_bounds__(256) void conv1d_train_main(
    const float* __restrict__ x, const float* __restrict__ y,
    const float* __restrict__ kern, const float* __restrict__ bias,
    float* __restrict__ partial, int nb)
{
    __shared__ float kk[KSZ];
    __shared__ float P[KSZ];     // inclusive prefix sums of kernel
    __shared__ float xf[KSZ];    // x[b, 0..126]
    __shared__ float xl[KSZ];    // x[b, 3969..4095]
    __shared__ float red[8];     // per-wave (tot, corr)
    __shared__ float sc[1];      // broadcast dconv

    const int tid  = threadIdx.x;
    const int wave = tid >> 6;
    const int lane = tid & 63;

    if (tid < KSZ) kk[tid] = kern[tid];
    __syncthreads();
    if (tid < KSZ) {
        float s = 0.f;
        for (int j = 0; j <= tid; ++j) s += kk[j];   // broadcast reads
        P[tid] = s;
    }
    __syncthreads();
    const float ksum = P[KSZ - 1];
    const float bs   = bias[0];

    float G_acc = 0.f, H_acc = 0.f;   // meaningful for tid < 127
    float C0_acc = 0.f, db_acc = 0.f; // meaningful for tid == 0

    for (int b = blockIdx.x; b < BATCH; b += nb) {
        const float* xr = x + (size_t)b * SEQ_LEN;
        float yv = 0.f;
        if (tid == 0) yv = y[b];      // issued early, used after reduce

        float tot = 0.f;
#pragma unroll
        for (int i = 0; i < 4; ++i) {
            const int base = i * 1024 + tid * 4;
            const float4 v = *reinterpret_cast<const float4*>(xr + base);
            tot += (v.x + v.y) + (v.z + v.w);
            if (i == 0 && base < 127) {          // head: indices 0..126
                xf[base] = v.x;
                if (base + 1 < 127) xf[base + 1] = v.y;
                if (base + 2 < 127) xf[base + 2] = v.z;
                if (base + 3 < 127) xf[base + 3] = v.w;
            }
            if (i == 3) {                        // tail: indices 3969..4095
                const int m = base - 3969;       // xl[m] = x[3969+m]
                if (m + 3 >= 0) {
                    if (m     >= 0) xl[m]     = v.x;
                    if (m + 1 >= 0) xl[m + 1] = v.y;
                    if (m + 2 >= 0) xl[m + 2] = v.z;
                    if (m + 3 >= 0) xl[m + 3] = v.w;
                }
            }
        }
        __syncthreads();   // xf/xl visible

        // edge correction: dot(x, c) = ksum*total + sum_j corr_j
        float corr = 0.f;
        if (tid < 127) corr = xf[tid] * (P[tid] - ksum) - xl[tid] * P[tid];

        float t = tot, c = corr;
#pragma unroll
        for (int off = 32; off >= 1; off >>= 1) {
            t += __shfl_down(t, off, 64);
            c += __shfl_down(c, off, 64);
        }
        if (lane == 0) { red[wave * 2] = t; red[wave * 2 + 1] = c; }
        __syncthreads();

        if (tid == 0) {
            const float tA = (red[0] + red[2]) + (red[4] + red[6]);
            const float cA = (red[1] + red[3]) + (red[5] + red[7]);
            const float logits = (ksum * tA + cA) * (1.f / (float)OUT_LEN) + bs;
            const float sig    = 1.f / (1.f + expf(-logits));
            const float dconv  = (sig - yv) * (1.f / (float)OUT_LEN);
            sc[0]   = dconv;
            C0_acc += dconv * tA;
            db_acc += dconv;
        }
        __syncthreads();

        const float dconv = sc[0];
        if (tid < 127) {
            G_acc += dconv * xf[tid];
            H_acc += dconv * xl[tid];
        }
        __syncthreads();   // protect xf/xl/red/sc before next row
    }

    float* pblk = partial + (size_t)blockIdx.x * 256;
    if (tid < 127) { pblk[tid] = G_acc; pblk[128 + tid] = H_acc; }
    if (tid == 0)  { pblk[127] = C0_acc; pblk[255] = db_acc; }
}

// Final reduce: column-sum the nb x 256 partials (4 slices x 256 cols in one
// 1024-thread block), then the one-time 127-step prefix/suffix scan.
__global__ __launch_bounds__(1024) void conv1d_train_reduce(
    const float* __restrict__ partial, int nb,
    const float* __restrict__ kern, const float* __restrict__ bias,
    float* __restrict__ out)
{
    const int tid   = threadIdx.x;
    const int col   = tid & 255;
    const int slice = tid >> 8;                 // 0..3
    const int chunk = (nb + 3) >> 2;
    const int lo    = slice * chunk;
    const int hi    = min(nb, lo + chunk);

    float a0 = 0.f, a1 = 0.f, a2 = 0.f, a3 = 0.f;
    float a4 = 0.f, a5 = 0.f, a6 = 0.f, a7 = 0.f;
    int i = lo;
    for (; i + 8 <= hi; i += 8) {
        a0 += partial[(size_t)(i + 0) * 256 + col];
        a1 += partial[(size_t)(i + 1) * 256 + col];
        a2 += partial[(size_t)(i + 2) * 256 + col];
        a3 += partial[(size_t)(i + 3) * 256 + col];
        a4 += partial[(size_t)(i + 4) * 256 + col];
        a5 += partial[(size_t)(i + 5) * 256 + col];
        a6 += partial[(size_t)(i + 6) * 256 + col];
        a7 += partial[(size_t)(i + 7) * 256 + col];
    }
    for (; i < hi; ++i) a0 += partial[(size_t)i * 256 + col];
    const float s = ((a0 + a1) + (a2 + a3)) + ((a4 + a5) + (a6 + a7));

    __shared__ float sl[4][256];
    __shared__ float colsum[256];
    sl[slice][col] = s;
    __syncthreads();
    if (tid < 256)
        colsum[tid] = (sl[0][tid] + sl[1][tid]) + (sl[2][tid] + sl[3][tid]);
    __syncthreads();

    if (tid < 128) {
        const float C0 = colsum[127];
        float pre = 0.f, suf = 0.f;
        for (int j = 0; j < 127; ++j) {
            const float g = colsum[j];         // broadcast
            const float h = colsum[128 + j];
            if (j < tid)  pre += g;
            if (j >= tid) suf += h;
        }
        const float dk = (C0 - pre - suf) * (1.f / (float)BATCH);
        out[tid] = kern[tid] - dk;
    }
    if (tid == 0) {
        const float db = colsum[255] * ((float)OUT_LEN / (float)BATCH);
        out[128] = bias[0] - db;
    }
}

extern "C" void kernel_launch(void* const* d_in, const int* in_sizes, int n_in,
                              void* d_out, int out_size, void* d_ws, size_t ws_size,
                              hipStream_t stream) {
    (void)in_sizes; (void)n_in; (void)out_size;
    const float* x    = (const float*)d_in[0];
    const float* y    = (const float*)d_in[1];
    const float* kern = (const float*)d_in[2];
    const float* bias = (const float*)d_in[3];
    float* out     = (float*)d_out;
    float* partial = (float*)d_ws;

    int nb = (int)(ws_size / (256 * sizeof(float)));
    if (nb > NB_MAX) nb = NB_MAX;
    if (nb < 1) nb = 1;

    hipLaunchKernelGGL(conv1d_train_main, dim3(nb), dim3(256), 0, stream,
                       x, y, kern, bias, partial, nb);
    hipLaunchKernelGGL(conv1d_train_reduce, dim3(1), dim3(1024), 0, stream,
                       partial, nb, kern, bias, out);
}